// Round 13
// baseline (392.150 us; speedup 1.0000x reference)
//
#include <hip/hip_runtime.h>
#include <cstdint>
#include <cstddef>

#define NS 4096
#define TS 16
#define DF 5
#define HD 128
#define EE 32768
#define EDD 32

typedef _Float16 h16;
typedef __attribute__((ext_vector_type(8))) _Float16 f16x8;
typedef __attribute__((ext_vector_type(2))) __fp16 fp16x2_n;  // builtin's native type
typedef __attribute__((ext_vector_type(4))) float f32x4;

__device__ __forceinline__ float sigmoidf_(float x){ return 1.f/(1.f+__expf(-x)); }
__device__ __forceinline__ float tanhf_(float x){ return 1.f - 2.f/(1.f+__expf(2.f*x)); }
__device__ __forceinline__ float leaky_(float x){ return x >= 0.f ? x : 0.2f*x; }

__device__ __forceinline__ unsigned pkh(float a, float b){
  union { fp16x2_n h; unsigned u; } x;
  x.h = __builtin_amdgcn_cvt_pkrtz(a, b);
  return x.u;
}
__device__ __forceinline__ void unpkh(unsigned u, float& a, float& b){
  union { unsigned u; fp16x2_n h; } x; x.u = u;
  a = (float)x.h.x; b = (float)x.h.y;
}
__device__ __forceinline__ f16x8 ld_h8(const h16* p){
  union { uint4 u; f16x8 v; } x; x.u = *(const uint4*)p; return x.v;
}

// ================= generic MFMA GEMM device function (fp16) =================
template<int AH, int CH>
__device__ __forceinline__ void gemm_dev(const void* Av, int lda,
    const float* __restrict__ Bp, int ldb, const float* __restrict__ bp,
    void* Cv, int ldc, int K, int act, size_t m0,
    h16* Asb, h16* Bsb)
{
  int tid = threadIdx.x;
  int wv = tid>>6, lane = tid&63, lm = lane&15, lq = lane>>4;
  f32x4 acc[2][8];
  #pragma unroll
  for (int mt=0;mt<2;mt++)
    #pragma unroll
    for (int nt=0;nt<8;nt++)
      acc[mt][nt] = (f32x4){0.f,0.f,0.f,0.f};

  for (int k0=0; k0<K; k0+=32){
    if (AH){
      const h16* A = (const h16*)Av;
      #pragma unroll
      for (int rep=0;rep<2;rep++){
        int idx = tid + rep*256;
        int row = idx>>2, c8 = idx&3;
        *(uint4*)&Asb[row*40 + c8*8] = *(const uint4*)&A[(m0+row)*(size_t)lda + k0 + c8*8];
      }
    } else {
      const float* A = (const float*)Av;
      #pragma unroll
      for (int rep=0;rep<4;rep++){
        int idx = tid + rep*256;
        int row = idx>>3, c4 = idx&7;
        float4 a = *(const float4*)&A[(m0+row)*(size_t)lda + k0 + c4*4];
        *(uint2*)&Asb[row*40 + c4*4] = make_uint2(pkh(a.x,a.y), pkh(a.z,a.w));
      }
    }
    #pragma unroll
    for (int rep=0;rep<4;rep++){
      int idx = tid + rep*256;
      int row = idx>>3, c4 = idx&7;
      float4 b = *(const float4*)&Bp[(size_t)row*ldb + k0 + c4*4];
      *(uint2*)&Bsb[row*40 + c4*4] = make_uint2(pkh(b.x,b.y), pkh(b.z,b.w));
    }
    __syncthreads();
    f16x8 afr[2], bfr[8];
    #pragma unroll
    for (int mt=0;mt<2;mt++)
      afr[mt] = ld_h8(&Asb[(wv*32 + mt*16 + lm)*40 + lq*8]);
    #pragma unroll
    for (int nt=0;nt<8;nt++)
      bfr[nt] = ld_h8(&Bsb[(nt*16 + lm)*40 + lq*8]);
    #pragma unroll
    for (int mt=0;mt<2;mt++)
      #pragma unroll
      for (int nt=0;nt<8;nt++)
        acc[mt][nt] = __builtin_amdgcn_mfma_f32_16x16x32_f16(afr[mt], bfr[nt], acc[mt][nt], 0,0,0);
    __syncthreads();
  }

  #pragma unroll
  for (int mt=0;mt<2;mt++){
    #pragma unroll
    for (int nt=0;nt<8;nt++){
      int col = nt*16 + lm;
      float bv = bp[col];
      #pragma unroll
      for (int i=0;i<4;i++){
        float o = acc[mt][nt][i] + bv;
        if (act) o = leaky_(o);
        size_t ridx = (m0 + wv*32 + mt*16 + lq*4 + i)*(size_t)ldc + col;
        if (CH) ((h16*)Cv)[ridx] = (h16)o;
        else    ((float*)Cv)[ridx] = o;
      }
    }
  }
}

// ================= LSTM 8 rows/block device function (fp16 MFMA) =================
__device__ void lstm8_dev(int blk, const float* __restrict__ sf,
                          const h16* __restrict__ WhhH,
                          const float* __restrict__ Wih, const float* __restrict__ bih,
                          const float* __restrict__ bhh, h16* __restrict__ cat,
                          char* smem)
{
  float* gates = (float*)smem;                 // 8*516*4 = 16512
  h16* hbuf = (h16*)(smem+16512);              // 8*136*2 = 2176
  float* sfb = (float*)(smem+16512+2176);      // 8*80*4  = 2560
  int tid = threadIdx.x;
  int n0 = blk*8;
  int wv = tid>>6, lane = tid&63, lm = lane&15, lq = lane>>4;

  f16x8 bfr[8][4];
  #pragma unroll
  for (int nt=0;nt<8;nt++){
    int g = wv*128 + nt*16 + lm;
    #pragma unroll
    for (int kt=0;kt<4;kt++)
      bfr[nt][kt] = *(const f16x8*)&WhhH[g*128 + kt*32 + lq*8];
  }

  int j = tid & 127;
  int rb = tid >> 7;
  float wih[4][5]; float bsum[4];
  #pragma unroll
  for (int gi=0; gi<4; gi++){
    int gc = gi*128 + j;
    #pragma unroll
    for (int d=0; d<5; d++) wih[gi][d] = Wih[gc*5+d];
    bsum[gi] = bih[gc] + bhh[gc];
  }
  float cst[4] = {0.f,0.f,0.f,0.f};

  for (int i=tid;i<544;i+=256) ((unsigned*)hbuf)[i] = 0;
  for (int i=tid;i<640;i+=256) sfb[i] = sf[(size_t)n0*80 + i];
  __syncthreads();

  f16x8 zf = {0,0,0,0,0,0,0,0};
  for (int t=0;t<16;t++){
    f16x8 af[4];
    #pragma unroll
    for (int kt=0;kt<4;kt++)
      af[kt] = (lm < 8) ? *(const f16x8*)&hbuf[lm*136 + kt*32 + lq*8] : zf;
    #pragma unroll
    for (int nt=0;nt<8;nt++){
      f32x4 acc = {0.f,0.f,0.f,0.f};
      #pragma unroll
      for (int kt=0;kt<4;kt++)
        acc = __builtin_amdgcn_mfma_f32_16x16x32_f16(af[kt], bfr[nt][kt], acc, 0,0,0);
      if (lq < 2){
        int col = wv*128 + nt*16 + lm;
        #pragma unroll
        for (int i=0;i<4;i++)
          gates[(lq*4+i)*516 + col] = acc[i];
      }
    }
    __syncthreads();
    #pragma unroll
    for (int q=0;q<4;q++){
      int r = rb + 2*q;
      const float* s = &sfb[r*80 + t*5];
      float pre[4];
      #pragma unroll
      for (int gi=0;gi<4;gi++){
        float a = bsum[gi];
        #pragma unroll
        for (int d=0;d<5;d++) a = fmaf(s[d], wih[gi][d], a);
        pre[gi] = a + gates[r*516 + gi*128 + j];
      }
      float iv = sigmoidf_(pre[0]);
      float fv = sigmoidf_(pre[1]);
      float gv = tanhf_(pre[2]);
      float ov = sigmoidf_(pre[3]);
      float c = fv*cst[q] + iv*gv;
      cst[q] = c;
      float h = ov*tanhf_(c);
      h16 hh = (h16)h;
      hbuf[r*136 + j] = hh;
      cat[(size_t)((n0+r)*16 + t)*512 + j] = hh;
    }
    __syncthreads();
  }
}

// ======== prolog: zero cnt | sf | cvt Whh | cvt Wr[3] | cvt Wq[3] ========
struct PP { const float* Wr[3]; const float* Wq[3]; };
__global__ __launch_bounds__(256)
void k_prolog(const float* __restrict__ x, float* __restrict__ sf,
              const float* __restrict__ Whh, h16* __restrict__ whhH,
              int* __restrict__ cnt, PP wr, h16* __restrict__ wrH,
              h16* __restrict__ wqH)
{
  int b = blockIdx.x, tid = threadIdx.x;
  if (b < 48){
    int i = b*256 + tid;
    if (i < 3*4096) cnt[i] = 0;
  } else if (b < 128){
    int id = (b-48)*256 + tid;
    if (id < NS*DF){
      int n = id / DF, d = id % DF;
      const float* xp = x + (size_t)n*TS*DF + d;
      float s = 0.f;
      #pragma unroll
      for (int t=0;t<TS;t++) s += xp[t*DF];
      float inv = (float)TS / s;
      float* sp = sf + (size_t)n*TS*DF + d;
      #pragma unroll
      for (int t=0;t<TS;t++) sp[t*DF] = xp[t*DF]*inv;
    }
  } else if (b < 384){
    int i = (b-128)*256 + tid;
    whhH[i] = (h16)Whh[i];
  } else if (b < 576){
    int i = (b-384)*256 + tid;   // 0..49151
    int g = i >> 14, r = i & 16383;
    wrH[i] = (h16)wr.Wr[g][r];
  } else {
    int i = (b-576)*256 + tid;   // 0..49151
    int g = i >> 14, r = i & 16383;
    wqH[i] = (h16)wr.Wq[g][r];
  }
}

// ================= mega1: lstm (512) | ee GEMM (768) | count+fill (384) ==========
struct M1 {
  const float *sf, *Wih, *bih, *bhh;
  const h16* WhhH;
  h16* cat;
  const float *ef[3]; const float *We[3]; const float *be[3];
  h16* eeb;
  const int* dst[3]; const int* src[3];
  int* cnt;
  int2* eidx2;
};
__global__ __launch_bounds__(256,2)
void k_mega1(M1 p)
{
  __shared__ __align__(16) char smem[21504];
  int b = blockIdx.x;
  if (b < 512){
    lstm8_dev(b, p.sf, p.WhhH, p.Wih, p.bih, p.bhh, p.cat, smem);
  } else if (b < 1280){
    int idx = b - 512;
    int proj = idx % 3, mt = idx / 3;
    h16* Asb = (h16*)smem;
    h16* Bsb = Asb + 128*40;
    gemm_dev<0,1>(p.ef[proj], 32, p.We[proj], 32, p.be[proj],
                  p.eeb + (size_t)proj*EE*128, 128, 32, 0, (size_t)mt*128, Asb, Bsb);
  } else {
    int idx = b - 1280;
    int g = idx >> 7, blk = idx & 127;
    int e = blk*256 + threadIdx.x;
    int d = p.dst[g][e];
    int s = p.src[g][e];
    int pos = atomicAdd(&p.cnt[g*4096 + d], 1);
    if (pos < 32) p.eidx2[((size_t)(g*4096 + d))*32 + pos] = make_int2(e, s);
  }
}

// ================= mega2: Wk GEMMs only, grid (3,512) =================
struct M2 {
  const h16* cat;
  const float* Wk[3]; const float* bk[3];
  h16* ekb;
};
__global__ __launch_bounds__(256)
void k_mega2(M2 p)
{
  __shared__ __align__(16) h16 Asb[128*40];
  __shared__ __align__(16) h16 Bsb[128*40];
  int proj = blockIdx.x;
  size_t m0 = (size_t)blockIdx.y * 128;
  gemm_dev<1,1>(p.cat, 512, p.Wk[proj], 128, p.bk[proj],
                p.ekb + (size_t)proj*NS*TS*128, 128, 128, 0, m0, Asb, Bsb);
}

// ====== k_edgewr v3: eq MFMA + gather/segment-sum + Wr MFMA, per (n,g) ======
struct EWP { const float* bq[3]; const float* br[3]; };
__global__ __launch_bounds__(256)
void k_edgewr(const h16* __restrict__ ekb, const h16* __restrict__ eeb,
              const int* __restrict__ cnt, const int2* __restrict__ eidx2,
              const h16* __restrict__ wqH, const h16* __restrict__ wrH,
              EWP wp, h16* __restrict__ cat)
{
  __shared__ __align__(16) h16 srS[16*136];    // 4352 B
  __shared__ __align__(16) h16 eqS[16*136];    // 4352 B
  __shared__ __align__(16) h16 ftS[16*136];    // 4352 B
  int n = blockIdx.x;
  int g = blockIdx.y;
  const h16* ekg = ekb + (size_t)g*NS*TS*128;
  const h16* eeg = eeb + (size_t)g*EE*128;
  int tid = threadIdx.x;
  int wv = tid>>6, lane = tid&63, lm = lane&15, lq = lane>>4;
  int t = tid>>4, hb = (tid&15)*8;

  // stage sr[n] tile (cat cols 0..127): one uint4 per thread
  *(uint4*)&srS[t*136 + hb] =
      *(const uint4*)&cat[((size_t)(n*16+t))*512 + hb];
  __syncthreads();

  // eq = sr @ Wq^T + bq  (wave wv computes nt = 2wv, 2wv+1)
  {
    f16x8 af[4];
    #pragma unroll
    for (int kt=0;kt<4;kt++)
      af[kt] = ld_h8(&srS[lm*136 + kt*32 + lq*8]);
    const h16* wqg = wqH + (size_t)g*128*128;
    const float* bq = wp.bq[g];
    #pragma unroll
    for (int nn=0; nn<2; nn++){
      int nt = wv*2 + nn;
      f32x4 a2 = {0.f,0.f,0.f,0.f};
      #pragma unroll
      for (int kt=0;kt<4;kt++){
        f16x8 bf = ld_h8(&wqg[(nt*16+lm)*128 + kt*32 + lq*8]);
        a2 = __builtin_amdgcn_mfma_f32_16x16x32_f16(af[kt], bf, a2, 0,0,0);
      }
      int colg = nt*16 + lm;
      float bv = bq[colg];
      #pragma unroll
      for (int i=0;i<4;i++)
        eqS[(lq*4+i)*136 + colg] = (h16)(a2[i] + bv);
    }
  }
  __syncthreads();

  // gather + segment sum
  f16x8 eqv = ld_h8(&eqS[t*136 + hb]);
  const f16x8 c02 = {(h16)0.2f,(h16)0.2f,(h16)0.2f,(h16)0.2f,
                     (h16)0.2f,(h16)0.2f,(h16)0.2f,(h16)0.2f};
  float acc[8];
  #pragma unroll
  for (int j=0;j<8;j++) acc[j]=0.f;
  int ne = cnt[g*4096 + n]; if (ne > 32) ne = 32;
  const int2* el = eidx2 + ((size_t)(g*4096 + n))*32;
  for (int i=0;i<ne;i++){
    int2 es = el[i];
    f16x8 kv = ld_h8(&ekg[((size_t)(es.y*16+t))*128 + hb]);
    f16x8 ev = ld_h8(&eeg[(size_t)es.x*128 + hb]);
    f16x8 x = eqv + kv + ev;
    f16x8 lk = __builtin_elementwise_max(x, x*c02);
    #pragma unroll
    for (int j=0;j<8;j++) acc[j] += (float)lk[j];
  }
  uint4 o;
  o.x = pkh(acc[0],acc[1]); o.y = pkh(acc[2],acc[3]);
  o.z = pkh(acc[4],acc[5]); o.w = pkh(acc[6],acc[7]);
  *(uint4*)&ftS[t*136 + hb] = o;
  __syncthreads();

  // [16,128] @ Wr^T via MFMA
  f16x8 af[4];
  #pragma unroll
  for (int kt=0;kt<4;kt++)
    af[kt] = ld_h8(&ftS[lm*136 + kt*32 + lq*8]);
  const h16* wrg = wrH + (size_t)g*128*128;
  const float* br = wp.br[g];
  h16* catp = cat + (size_t)(1+g)*128;
  #pragma unroll
  for (int nn=0; nn<2; nn++){
    int nt = wv*2 + nn;
    f32x4 a2 = {0.f,0.f,0.f,0.f};
    #pragma unroll
    for (int kt=0;kt<4;kt++){
      f16x8 bf = ld_h8(&wrg[(nt*16+lm)*128 + kt*32 + lq*8]);
      a2 = __builtin_amdgcn_mfma_f32_16x16x32_f16(af[kt], bf, a2, 0,0,0);
    }
    int colg = nt*16 + lm;
    float bv = br[colg];
    #pragma unroll
    for (int i=0;i<4;i++){
      int row = lq*4 + i;
      catp[((size_t)(n*16+row))*512 + colg] = (h16)(a2[i] + bv);
    }
  }
}

// ================= attention + pooling (fp16 cat/pooled) =================
__global__ __launch_bounds__(256)
void k_attn(const h16* __restrict__ cat, const float* __restrict__ attnW,
            const float* __restrict__ attnB, h16* __restrict__ pooled)
{
  __shared__ h16 ct[16*512];
  __shared__ float sred[4][16];
  int n = blockIdx.x, tid = threadIdx.x;
  {
    const uint4* srcp = (const uint4*)(cat + (size_t)n*8192);
    uint4* dstp = (uint4*)ct;
    for (int i=tid;i<1024;i+=256) dstp[i] = srcp[i];
  }
  __syncthreads();
  int c0 = tid*2;
  float w0 = attnW[c0], w1 = attnW[c0+1];
  const unsigned* ctu = (const unsigned*)ct;
  float loc[16];
  #pragma unroll
  for (int t=0;t<16;t++){
    float a,b; unpkh(ctu[t*256 + tid], a, b);
    loc[t] = a*w0 + b*w1;
  }
  #pragma unroll
  for (int t=0;t<16;t++){
    float v = loc[t];
    for (int off=1; off<64; off<<=1) v += __shfl_xor(v, off, 64);
    loc[t]=v;
  }
  int wave = tid >> 6, lane = tid & 63;
  if (lane==0){
    #pragma unroll
    for (int t=0;t<16;t++) sred[wave][t]=loc[t];
  }
  __syncthreads();
  float s[16]; float m=-1e30f;
  float ab = attnB[0];
  #pragma unroll
  for (int t=0;t<16;t++){ s[t] = sred[0][t]+sred[1][t]+sred[2][t]+sred[3][t] + ab; m = fmaxf(m, s[t]); }
  float sum=0.f;
  #pragma unroll
  for (int t=0;t<16;t++){ s[t] = __expf(s[t]-m); sum += s[t]; }
  float inv = 1.f/sum;
  float p0=0.f,p1=0.f;
  #pragma unroll
  for (int t=0;t<16;t++){
    float a = s[t]*inv;
    float x,y; unpkh(ctu[t*256 + tid], x, y);
    p0 = fmaf(x, a, p0); p1 = fmaf(y, a, p1);
  }
  ((unsigned*)pooled)[(size_t)n*256 + tid] = pkh(p0,p1);
}

// ================= MLP1 GEMM + fused final: grid 32 =================
__global__ __launch_bounds__(256)
void k_mlp(const h16* __restrict__ pooled, const float* __restrict__ W1,
           const float* __restrict__ b1, h16* __restrict__ hmlp,
           const float* __restrict__ W2, const float* __restrict__ b2,
           const float* __restrict__ sf, float* __restrict__ out)
{
  __shared__ __align__(16) h16 Asb[128*40];
  __shared__ __align__(16) h16 Bsb[128*40];
  size_t m0 = (size_t)blockIdx.x*128;
  gemm_dev<1,1>(pooled, 512, W1, 512, b1, hmlp, 128, 512, 1, m0, Asb, Bsb);
  __syncthreads();
  int tid = threadIdx.x;
  int r = tid >> 1, o64 = (tid & 1)*64;
  const h16* hp = hmlp + (m0 + r)*128 + o64;
  float acc = 0.f;
  #pragma unroll
  for (int c=0; c<64; c++) acc = fmaf((float)hp[c], W2[o64 + c], acc);
  acc += __shfl_xor(acc, 1, 64);
  if ((tid & 1) == 0){
    float o = leaky_(acc + b2[0]);
    size_t n = m0 + r;
    out[n] = o / sf[n*80 + 75] - 1.f;
  }
}

extern "C" void kernel_launch(void* const* d_in, const int* in_sizes, int n_in,
                              void* d_out, int out_size, void* d_ws, size_t ws_size,
                              hipStream_t stream)
{
  const float* x    = (const float*)d_in[0];
  const float* Wih  = (const float*)d_in[34];
  const float* Whh  = (const float*)d_in[35];
  const float* bih  = (const float*)d_in[36];
  const float* bhh  = (const float*)d_in[37];
  const float* attnW= (const float*)d_in[38];
  const float* attnB= (const float*)d_in[39];
  const float* W1   = (const float*)d_in[40];
  const float* b1   = (const float*)d_in[41];
  const float* W2   = (const float*)d_in[42];
  const float* b2   = (const float*)d_in[43];

  char* w = (char*)d_ws;
  size_t o = 0;
  h16* cat    = (h16*)(w+o); o += (size_t)NS*TS*512*2;      // 64 MiB
  h16* ekb    = (h16*)(w+o); o += (size_t)3*NS*TS*128*2;    // 48 MiB
  h16* eeb    = (h16*)(w+o); o += (size_t)3*EE*128*2;       // 24 MiB
  h16* pooled = (h16*)(w+o); o += (size_t)NS*512*2;         // 4 MiB
  float* sf   = (float*)(w+o); o += (size_t)NS*TS*DF*4;
  h16* hmlp   = (h16*)(w+o); o += (size_t)NS*HD*2;
  h16* whhH   = (h16*)(w+o); o += (size_t)512*128*2;
  h16* wrH    = (h16*)(w+o); o += (size_t)3*128*128*2;
  h16* wqH    = (h16*)(w+o); o += (size_t)3*128*128*2;
  int* cnt    = (int*)(w+o); o += 3*4096*4;
  int2* eidx2 = (int2*)(w+o); o += (size_t)3*4096*32*8;     // 3 MiB

  // D1: prolog = zero cnt | sf | cvt Whh | cvt Wr | cvt Wq
  {
    PP pp;
    for (int g=0; g<3; g++){
      pp.Wr[g] = (const float*)d_in[1 + g*11 + 9];
      pp.Wq[g] = (const float*)d_in[1 + g*11 + 3];
    }
    k_prolog<<<768, 256, 0, stream>>>(x, sf, Whh, whhH, cnt, pp, wrH, wqH);
  }

  // D2: mega1 = lstm | ee GEMM | count+fill (padded CSR)
  {
    M1 p;
    p.sf = sf; p.Wih = Wih; p.bih = bih; p.bhh = bhh;
    p.WhhH = whhH; p.cat = cat; p.eeb = eeb; p.cnt = cnt; p.eidx2 = eidx2;
    for (int g=0; g<3; g++){
      int base = 1 + g*11;
      p.src[g] = (const int*)d_in[base+0];
      p.dst[g] = (const int*)d_in[base+1];
      p.ef[g] = (const float*)d_in[base+2];
      p.We[g] = (const float*)d_in[base+7];
      p.be[g] = (const float*)d_in[base+8];
    }
    k_mega1<<<1664, 256, 0, stream>>>(p);
  }

  // D3: mega2 = Wk GEMMs only
  {
    M2 p;
    p.cat = cat; p.ekb = ekb;
    for (int g=0; g<3; g++){
      int base = 1 + g*11;
      p.Wk[g] = (const float*)d_in[base+5];
      p.bk[g] = (const float*)d_in[base+6];
    }
    k_mega2<<<dim3(3,512), 256, 0, stream>>>(p);
  }

  // D4: eq MFMA + edge gather + Wr projection fused
  {
    EWP wp;
    for (int g=0; g<3; g++){
      wp.bq[g] = (const float*)d_in[1 + g*11 + 4];
      wp.br[g] = (const float*)d_in[1 + g*11 + 10];
    }
    k_edgewr<<<dim3(NS,3), 256, 0, stream>>>(ekb, eeb, cnt, eidx2, wqH, wrH, wp, cat);
  }

  // D5: attention + pooling
  k_attn<<<NS, 256, 0, stream>>>(cat, attnW, attnB, pooled);
  // D6: MLP1 + final
  k_mlp<<<32, 256, 0, stream>>>(pooled, W1, b1, hmlp, W2, b2, sf, (float*)d_out);
}

// Round 14
// 346.237 us; speedup vs baseline: 1.1326x; 1.1326x over previous
//
#include <hip/hip_runtime.h>
#include <cstdint>
#include <cstddef>

#define NS 4096
#define TS 16
#define DF 5
#define HD 128
#define EE 32768
#define EDD 32

typedef _Float16 h16;
typedef __attribute__((ext_vector_type(8))) _Float16 f16x8;
typedef __attribute__((ext_vector_type(2))) __fp16 fp16x2_n;  // builtin's native type
typedef __attribute__((ext_vector_type(4))) float f32x4;

__device__ __forceinline__ float sigmoidf_(float x){ return 1.f/(1.f+__expf(-x)); }
__device__ __forceinline__ float tanhf_(float x){ return 1.f - 2.f/(1.f+__expf(2.f*x)); }
__device__ __forceinline__ float leaky_(float x){ return x >= 0.f ? x : 0.2f*x; }

__device__ __forceinline__ unsigned pkh(float a, float b){
  union { fp16x2_n h; unsigned u; } x;
  x.h = __builtin_amdgcn_cvt_pkrtz(a, b);
  return x.u;
}
__device__ __forceinline__ void unpkh(unsigned u, float& a, float& b){
  union { unsigned u; fp16x2_n h; } x; x.u = u;
  a = (float)x.h.x; b = (float)x.h.y;
}
__device__ __forceinline__ f16x8 ld_h8(const h16* p){
  union { uint4 u; f16x8 v; } x; x.u = *(const uint4*)p; return x.v;
}

// ================= generic MFMA GEMM device function (fp16) =================
template<int AH, int CH>
__device__ __forceinline__ void gemm_dev(const void* Av, int lda,
    const float* __restrict__ Bp, int ldb, const float* __restrict__ bp,
    void* Cv, int ldc, int K, int act, size_t m0,
    h16* Asb, h16* Bsb)
{
  int tid = threadIdx.x;
  int wv = tid>>6, lane = tid&63, lm = lane&15, lq = lane>>4;
  f32x4 acc[2][8];
  #pragma unroll
  for (int mt=0;mt<2;mt++)
    #pragma unroll
    for (int nt=0;nt<8;nt++)
      acc[mt][nt] = (f32x4){0.f,0.f,0.f,0.f};

  for (int k0=0; k0<K; k0+=32){
    if (AH){
      const h16* A = (const h16*)Av;
      #pragma unroll
      for (int rep=0;rep<2;rep++){
        int idx = tid + rep*256;
        int row = idx>>2, c8 = idx&3;
        *(uint4*)&Asb[row*40 + c8*8] = *(const uint4*)&A[(m0+row)*(size_t)lda + k0 + c8*8];
      }
    } else {
      const float* A = (const float*)Av;
      #pragma unroll
      for (int rep=0;rep<4;rep++){
        int idx = tid + rep*256;
        int row = idx>>3, c4 = idx&7;
        float4 a = *(const float4*)&A[(m0+row)*(size_t)lda + k0 + c4*4];
        *(uint2*)&Asb[row*40 + c4*4] = make_uint2(pkh(a.x,a.y), pkh(a.z,a.w));
      }
    }
    #pragma unroll
    for (int rep=0;rep<4;rep++){
      int idx = tid + rep*256;
      int row = idx>>3, c4 = idx&7;
      float4 b = *(const float4*)&Bp[(size_t)row*ldb + k0 + c4*4];
      *(uint2*)&Bsb[row*40 + c4*4] = make_uint2(pkh(b.x,b.y), pkh(b.z,b.w));
    }
    __syncthreads();
    f16x8 afr[2], bfr[8];
    #pragma unroll
    for (int mt=0;mt<2;mt++)
      afr[mt] = ld_h8(&Asb[(wv*32 + mt*16 + lm)*40 + lq*8]);
    #pragma unroll
    for (int nt=0;nt<8;nt++)
      bfr[nt] = ld_h8(&Bsb[(nt*16 + lm)*40 + lq*8]);
    #pragma unroll
    for (int mt=0;mt<2;mt++)
      #pragma unroll
      for (int nt=0;nt<8;nt++)
        acc[mt][nt] = __builtin_amdgcn_mfma_f32_16x16x32_f16(afr[mt], bfr[nt], acc[mt][nt], 0,0,0);
    __syncthreads();
  }

  #pragma unroll
  for (int mt=0;mt<2;mt++){
    #pragma unroll
    for (int nt=0;nt<8;nt++){
      int col = nt*16 + lm;
      float bv = bp[col];
      #pragma unroll
      for (int i=0;i<4;i++){
        float o = acc[mt][nt][i] + bv;
        if (act) o = leaky_(o);
        size_t ridx = (m0 + wv*32 + mt*16 + lq*4 + i)*(size_t)ldc + col;
        if (CH) ((h16*)Cv)[ridx] = (h16)o;
        else    ((float*)Cv)[ridx] = o;
      }
    }
  }
}

// ================= LSTM 8 rows/block (fp16 MFMA) — writes compact sr =========
__device__ void lstm8_dev(int blk, const float* __restrict__ sf,
                          const h16* __restrict__ WhhH,
                          const float* __restrict__ Wih, const float* __restrict__ bih,
                          const float* __restrict__ bhh, h16* __restrict__ srG,
                          char* smem)
{
  float* gates = (float*)smem;                 // 8*516*4 = 16512
  h16* hbuf = (h16*)(smem+16512);              // 8*136*2 = 2176
  float* sfb = (float*)(smem+16512+2176);      // 8*80*4  = 2560
  int tid = threadIdx.x;
  int n0 = blk*8;
  int wv = tid>>6, lane = tid&63, lm = lane&15, lq = lane>>4;

  f16x8 bfr[8][4];
  #pragma unroll
  for (int nt=0;nt<8;nt++){
    int g = wv*128 + nt*16 + lm;
    #pragma unroll
    for (int kt=0;kt<4;kt++)
      bfr[nt][kt] = *(const f16x8*)&WhhH[g*128 + kt*32 + lq*8];
  }

  int j = tid & 127;
  int rb = tid >> 7;
  float wih[4][5]; float bsum[4];
  #pragma unroll
  for (int gi=0; gi<4; gi++){
    int gc = gi*128 + j;
    #pragma unroll
    for (int d=0; d<5; d++) wih[gi][d] = Wih[gc*5+d];
    bsum[gi] = bih[gc] + bhh[gc];
  }
  float cst[4] = {0.f,0.f,0.f,0.f};

  for (int i=tid;i<544;i+=256) ((unsigned*)hbuf)[i] = 0;
  for (int i=tid;i<640;i+=256) sfb[i] = sf[(size_t)n0*80 + i];
  __syncthreads();

  f16x8 zf = {0,0,0,0,0,0,0,0};
  for (int t=0;t<16;t++){
    f16x8 af[4];
    #pragma unroll
    for (int kt=0;kt<4;kt++)
      af[kt] = (lm < 8) ? *(const f16x8*)&hbuf[lm*136 + kt*32 + lq*8] : zf;
    #pragma unroll
    for (int nt=0;nt<8;nt++){
      f32x4 acc = {0.f,0.f,0.f,0.f};
      #pragma unroll
      for (int kt=0;kt<4;kt++)
        acc = __builtin_amdgcn_mfma_f32_16x16x32_f16(af[kt], bfr[nt][kt], acc, 0,0,0);
      if (lq < 2){
        int col = wv*128 + nt*16 + lm;
        #pragma unroll
        for (int i=0;i<4;i++)
          gates[(lq*4+i)*516 + col] = acc[i];
      }
    }
    __syncthreads();
    #pragma unroll
    for (int q=0;q<4;q++){
      int r = rb + 2*q;
      const float* s = &sfb[r*80 + t*5];
      float pre[4];
      #pragma unroll
      for (int gi=0;gi<4;gi++){
        float a = bsum[gi];
        #pragma unroll
        for (int d=0;d<5;d++) a = fmaf(s[d], wih[gi][d], a);
        pre[gi] = a + gates[r*516 + gi*128 + j];
      }
      float iv = sigmoidf_(pre[0]);
      float fv = sigmoidf_(pre[1]);
      float gv = tanhf_(pre[2]);
      float ov = sigmoidf_(pre[3]);
      float c = fv*cst[q] + iv*gv;
      cst[q] = c;
      float h = ov*tanhf_(c);
      h16 hh = (h16)h;
      hbuf[r*136 + j] = hh;
      srG[(size_t)((n0+r)*16 + t)*128 + j] = hh;
    }
    __syncthreads();
  }
}

// ======== prolog: zero cnt | sf | cvt Whh | cvt Wr[3] ========
struct PP { const float* Wr[3]; };
__global__ __launch_bounds__(256)
void k_prolog(const float* __restrict__ x, float* __restrict__ sf,
              const float* __restrict__ Whh, h16* __restrict__ whhH,
              int* __restrict__ cnt, PP wr, h16* __restrict__ wrH)
{
  int b = blockIdx.x, tid = threadIdx.x;
  if (b < 48){
    int i = b*256 + tid;
    if (i < 3*4096) cnt[i] = 0;
  } else if (b < 128){
    int id = (b-48)*256 + tid;
    if (id < NS*DF){
      int n = id / DF, d = id % DF;
      const float* xp = x + (size_t)n*TS*DF + d;
      float s = 0.f;
      #pragma unroll
      for (int t=0;t<TS;t++) s += xp[t*DF];
      float inv = (float)TS / s;
      float* sp = sf + (size_t)n*TS*DF + d;
      #pragma unroll
      for (int t=0;t<TS;t++) sp[t*DF] = xp[t*DF]*inv;
    }
  } else if (b < 384){
    int i = (b-128)*256 + tid;
    whhH[i] = (h16)Whh[i];
  } else {
    int i = (b-384)*256 + tid;   // 0..49151
    int g = i >> 14, r = i & 16383;
    wrH[i] = (h16)wr.Wr[g][r];
  }
}

// ================= mega1: lstm (512) | ee GEMM (768) | count+fill (384) ==========
struct M1 {
  const float *sf, *Wih, *bih, *bhh;
  const h16* WhhH;
  h16* srG;
  const float *ef[3]; const float *We[3]; const float *be[3];
  h16* eeb;
  const int* dst[3]; const int* src[3];
  int* cnt;
  int2* eidx2;
};
__global__ __launch_bounds__(256,2)
void k_mega1(M1 p)
{
  __shared__ __align__(16) char smem[21504];
  int b = blockIdx.x;
  if (b < 512){
    lstm8_dev(b, p.sf, p.WhhH, p.Wih, p.bih, p.bhh, p.srG, smem);
  } else if (b < 1280){
    int idx = b - 512;
    int proj = idx % 3, mt = idx / 3;
    h16* Asb = (h16*)smem;
    h16* Bsb = Asb + 128*40;
    gemm_dev<0,1>(p.ef[proj], 32, p.We[proj], 32, p.be[proj],
                  p.eeb + (size_t)proj*EE*128, 128, 32, 0, (size_t)mt*128, Asb, Bsb);
  } else {
    int idx = b - 1280;
    int g = idx >> 7, blk = idx & 127;
    int e = blk*256 + threadIdx.x;
    int d = p.dst[g][e];
    int s = p.src[g][e];
    int pos = atomicAdd(&p.cnt[g*4096 + d], 1);
    if (pos < 32) p.eidx2[((size_t)(g*4096 + d))*32 + pos] = make_int2(e, s);
  }
}

// ================= mega2: QK GEMMs (R12-proven), grid 3072 =================
struct M2 {
  const h16* srG;
  const float* W[6]; const float* bias[6];
  h16* eqk;
};
__global__ __launch_bounds__(256)
void k_mega2(M2 p)
{
  __shared__ __align__(16) h16 Asb[128*40];
  __shared__ __align__(16) h16 Bsb[128*40];
  int b = blockIdx.x;
  int proj = b % 6, mt = b / 6;
  gemm_dev<1,1>(p.srG, 128, p.W[proj], 128, p.bias[proj],
                p.eqk + (size_t)proj*NS*TS*128, 128, 128, 0, (size_t)mt*128, Asb, Bsb);
}

// ====== k_edgeattn: per node n — 3×(gather + Wr MFMA) + attention + pool ======
struct EWP { const float* br[3]; };
__global__ __launch_bounds__(256)
void k_edgeattn(const h16* __restrict__ srG, const h16* __restrict__ eqk,
                const h16* __restrict__ eeb, const int* __restrict__ cnt,
                const int2* __restrict__ eidx2, const h16* __restrict__ wrH,
                EWP wp, const float* __restrict__ attnW,
                const float* __restrict__ attnB, h16* __restrict__ pooled)
{
  __shared__ __align__(16) h16 ctS[16*520];    // 16640 B: full cat tile, pitch 520
  __shared__ __align__(16) h16 ftS[16*136];    // 4352 B
  __shared__ float sred[4][16];
  int n = blockIdx.x;
  int tid = threadIdx.x;
  int wv = tid>>6, lane = tid&63, lm = lane&15, lq = lane>>4;
  int t = tid>>4, hb = (tid&15)*8;

  // stage sr tile into ctS cols 0..127
  *(uint4*)&ctS[t*520 + hb] = *(const uint4*)&srG[((size_t)(n*16+t))*128 + hb];

  const f16x8 c02 = {(h16)0.2f,(h16)0.2f,(h16)0.2f,(h16)0.2f,
                     (h16)0.2f,(h16)0.2f,(h16)0.2f,(h16)0.2f};

  for (int g=0; g<3; g++){
    const h16* eqb = eqk + (size_t)(2*g)  *NS*TS*128;
    const h16* ekb = eqk + (size_t)(2*g+1)*NS*TS*128;
    const h16* eeg = eeb + (size_t)g*EE*128;

    size_t own = ((size_t)(n*16+t))*128 + hb;
    f16x8 eqv = ld_h8(&eqb[own]);
    float acc[8];
    #pragma unroll
    for (int j=0;j<8;j++) acc[j]=0.f;
    int ne = cnt[g*4096 + n]; if (ne > 32) ne = 32;
    const int2* el = eidx2 + ((size_t)(g*4096 + n))*32;
    for (int i=0;i<ne;i++){
      int2 es = el[i];
      f16x8 kv = ld_h8(&ekb[((size_t)(es.y*16+t))*128 + hb]);
      f16x8 ev = ld_h8(&eeg[(size_t)es.x*128 + hb]);
      f16x8 x = eqv + kv + ev;
      f16x8 lk = __builtin_elementwise_max(x, x*c02);
      #pragma unroll
      for (int j=0;j<8;j++) acc[j] += (float)lk[j];
    }
    uint4 o;
    o.x = pkh(acc[0],acc[1]); o.y = pkh(acc[2],acc[3]);
    o.z = pkh(acc[4],acc[5]); o.w = pkh(acc[6],acc[7]);
    *(uint4*)&ftS[t*136 + hb] = o;
    __syncthreads();

    // [16,128] @ Wr^T via MFMA -> ctS cols (1+g)*128
    f16x8 af[4];
    #pragma unroll
    for (int kt=0;kt<4;kt++)
      af[kt] = ld_h8(&ftS[lm*136 + kt*32 + lq*8]);
    const h16* wrg = wrH + (size_t)g*128*128;
    const float* br = wp.br[g];
    #pragma unroll
    for (int nn=0; nn<2; nn++){
      int nt = wv*2 + nn;
      f32x4 a2 = {0.f,0.f,0.f,0.f};
      #pragma unroll
      for (int kt=0;kt<4;kt++){
        f16x8 bf = ld_h8(&wrg[(nt*16+lm)*128 + kt*32 + lq*8]);
        a2 = __builtin_amdgcn_mfma_f32_16x16x32_f16(af[kt], bf, a2, 0,0,0);
      }
      int colg = (1+g)*128 + nt*16 + lm;
      float bv = br[nt*16 + lm];
      #pragma unroll
      for (int i=0;i<4;i++)
        ctS[(lq*4+i)*520 + colg] = (h16)(a2[i] + bv);
    }
    __syncthreads();   // ftS reused next g; ctS writes visible for attn
  }

  // ---- attention + pooling over the LDS cat tile ----
  int c0 = tid*2;
  float w0 = attnW[c0], w1 = attnW[c0+1];
  const unsigned* ctu = (const unsigned*)ctS;   // row pitch 260 words
  float loc[16];
  #pragma unroll
  for (int tt=0;tt<16;tt++){
    float a,b; unpkh(ctu[tt*260 + tid], a, b);
    loc[tt] = a*w0 + b*w1;
  }
  #pragma unroll
  for (int tt=0;tt<16;tt++){
    float v = loc[tt];
    for (int off=1; off<64; off<<=1) v += __shfl_xor(v, off, 64);
    loc[tt]=v;
  }
  if (lane==0){
    #pragma unroll
    for (int tt=0;tt<16;tt++) sred[wv][tt]=loc[tt];
  }
  __syncthreads();
  float s[16]; float m=-1e30f;
  float ab = attnB[0];
  #pragma unroll
  for (int tt=0;tt<16;tt++){ s[tt] = sred[0][tt]+sred[1][tt]+sred[2][tt]+sred[3][tt] + ab; m = fmaxf(m, s[tt]); }
  float sum=0.f;
  #pragma unroll
  for (int tt=0;tt<16;tt++){ s[tt] = __expf(s[tt]-m); sum += s[tt]; }
  float inv = 1.f/sum;
  float p0=0.f,p1=0.f;
  #pragma unroll
  for (int tt=0;tt<16;tt++){
    float a = s[tt]*inv;
    float x,y; unpkh(ctu[tt*260 + tid], x, y);
    p0 = fmaf(x, a, p0); p1 = fmaf(y, a, p1);
  }
  ((unsigned*)pooled)[(size_t)n*256 + tid] = pkh(p0,p1);
}

// ================= MLP1 GEMM + fused final: grid 32 =================
__global__ __launch_bounds__(256)
void k_mlp(const h16* __restrict__ pooled, const float* __restrict__ W1,
           const float* __restrict__ b1, h16* __restrict__ hmlp,
           const float* __restrict__ W2, const float* __restrict__ b2,
           const float* __restrict__ sf, float* __restrict__ out)
{
  __shared__ __align__(16) h16 Asb[128*40];
  __shared__ __align__(16) h16 Bsb[128*40];
  size_t m0 = (size_t)blockIdx.x*128;
  gemm_dev<1,1>(pooled, 512, W1, 512, b1, hmlp, 128, 512, 1, m0, Asb, Bsb);
  __syncthreads();
  int tid = threadIdx.x;
  int r = tid >> 1, o64 = (tid & 1)*64;
  const h16* hp = hmlp + (m0 + r)*128 + o64;
  float acc = 0.f;
  #pragma unroll
  for (int c=0; c<64; c++) acc = fmaf((float)hp[c], W2[o64 + c], acc);
  acc += __shfl_xor(acc, 1, 64);
  if ((tid & 1) == 0){
    float o = leaky_(acc + b2[0]);
    size_t n = m0 + r;
    out[n] = o / sf[n*80 + 75] - 1.f;
  }
}

extern "C" void kernel_launch(void* const* d_in, const int* in_sizes, int n_in,
                              void* d_out, int out_size, void* d_ws, size_t ws_size,
                              hipStream_t stream)
{
  const float* x    = (const float*)d_in[0];
  const float* Wih  = (const float*)d_in[34];
  const float* Whh  = (const float*)d_in[35];
  const float* bih  = (const float*)d_in[36];
  const float* bhh  = (const float*)d_in[37];
  const float* attnW= (const float*)d_in[38];
  const float* attnB= (const float*)d_in[39];
  const float* W1   = (const float*)d_in[40];
  const float* b1   = (const float*)d_in[41];
  const float* W2   = (const float*)d_in[42];
  const float* b2   = (const float*)d_in[43];

  char* w = (char*)d_ws;
  size_t o = 0;
  h16* srG    = (h16*)(w+o); o += (size_t)NS*TS*128*2;      // 16 MiB
  h16* eqk    = (h16*)(w+o); o += (size_t)6*NS*TS*128*2;    // 96 MiB
  h16* eeb    = (h16*)(w+o); o += (size_t)3*EE*128*2;       // 24 MiB
  h16* pooled = (h16*)(w+o); o += (size_t)NS*512*2;         // 4 MiB
  float* sf   = (float*)(w+o); o += (size_t)NS*TS*DF*4;
  h16* hmlp   = (h16*)(w+o); o += (size_t)NS*HD*2;
  h16* whhH   = (h16*)(w+o); o += (size_t)512*128*2;
  h16* wrH    = (h16*)(w+o); o += (size_t)3*128*128*2;
  int* cnt    = (int*)(w+o); o += 3*4096*4;
  int2* eidx2 = (int2*)(w+o); o += (size_t)3*4096*32*8;     // 3 MiB

  // D1: prolog = zero cnt | sf | cvt Whh | cvt Wr
  {
    PP pp;
    for (int g=0; g<3; g++) pp.Wr[g] = (const float*)d_in[1 + g*11 + 9];
    k_prolog<<<576, 256, 0, stream>>>(x, sf, Whh, whhH, cnt, pp, wrH);
  }

  // D2: mega1 = lstm | ee GEMM | count+fill (padded CSR)
  {
    M1 p;
    p.sf = sf; p.Wih = Wih; p.bih = bih; p.bhh = bhh;
    p.WhhH = whhH; p.srG = srG; p.eeb = eeb; p.cnt = cnt; p.eidx2 = eidx2;
    for (int g=0; g<3; g++){
      int base = 1 + g*11;
      p.src[g] = (const int*)d_in[base+0];
      p.dst[g] = (const int*)d_in[base+1];
      p.ef[g] = (const float*)d_in[base+2];
      p.We[g] = (const float*)d_in[base+7];
      p.be[g] = (const float*)d_in[base+8];
    }
    k_mega1<<<1664, 256, 0, stream>>>(p);
  }

  // D3: mega2 = QK GEMMs (6 proj)
  {
    M2 p;
    p.srG = srG; p.eqk = eqk;
    for (int g=0; g<3; g++){
      int base = 1 + g*11;
      p.W[2*g]      = (const float*)d_in[base+3]; // Wq
      p.bias[2*g]   = (const float*)d_in[base+4];
      p.W[2*g+1]    = (const float*)d_in[base+5]; // Wk
      p.bias[2*g+1] = (const float*)d_in[base+6];
    }
    k_mega2<<<3072, 256, 0, stream>>>(p);
  }

  // D4: edge gather + Wr + attention + pooling fused, one block per node
  {
    EWP wp;
    for (int g=0; g<3; g++) wp.br[g] = (const float*)d_in[1 + g*11 + 10];
    k_edgeattn<<<NS, 256, 0, stream>>>(srG, eqk, eeb, cnt, eidx2, wrH, wp,
                                       attnW, attnB, pooled);
  }

  // D5: MLP1 + final
  k_mlp<<<32, 256, 0, stream>>>(pooled, W1, b1, hmlp, W2, b2, sf, (float*)d_out);
}